// Round 2
// baseline (1145.965 us; speedup 1.0000x reference)
//
#include <hip/hip_runtime.h>

// 3D neighborhood attention, window 3x3x3, over [B=2, 64,64,64, C=96], NH=6, HD=16.
// Inputs (float32): q [B,H,W,T,C], k [B,H,W,T,C], rpb [6,3,3,3].
// Output (float32): [B, 18, H, W, T]  (channel = head*3 + axis, axis in {di,dj,dl}).
//
// R5b: R4 + (a) software-pipelined staging: next pencil's global loads issued
// into registers DURING compute of the current pencil (R4 issued them right
// before the barrier that consumes them -> full latency exposed 9x/block);
// (b) XCD-chunked blockIdx swizzle so the 9x pencil reuse hits the 4MiB
// per-XCD L2 (round-robin dispatch put w-neighbors on different XCDs);
// (c) streaming exp-sum softmax (no sc[27], no second pass; |s|<=~8 so no
// max-subtraction needed in fp32); (d) nontemporal q/out (single-touch) to
// keep L2/L3 for k; (e) rpb staged to LDS once, uniform broadcast reads.
// (fix vs R5: nontemporal load needs a clang ext_vector type, not HIP float4)

typedef float f32x4 __attribute__((ext_vector_type(4)));

__global__ __launch_bounds__(384, 7) void natt3d_kernel(
    const float* __restrict__ q, const float* __restrict__ k,
    const float* __restrict__ rpb, float* __restrict__ out)
{
    // [c][t ^ (c&7)] in float4 units: c = 0..23 (16B channel chunk), t = 0..63.
    // Reads (fixed c, lane t): 16B-stride dense permutation -> conflict-free.
    // Writes (c fast across lanes): XOR spreads bank groups.
    __shared__ float4 lds[24 * 64];   // 24576 B
    __shared__ float rbs[6 * 27];     // rpb staged once, broadcast ds_reads

    // XCD-chunked swizzle: 8192 blocks = 8 XCDs x 1024 (bijective).
    // Each XCD walks contiguous (b,h,w) row-major -> neighbor pencils L2-hit.
    const int bid = (int)blockIdx.x;
    const int blk = ((bid & 7) << 10) | (bid >> 3);
    const int b = blk >> 12;
    const int h = (blk >> 6) & 63;
    const int w = blk & 63;
    const int tid = (int)threadIdx.x;
    const int n = tid >> 6;              // head 0..5 (wave-uniform)
    const int t = tid & 63;              // lane id = t

    if (tid < 6 * 27) rbs[tid] = rpb[tid];   // visible after first barrier

    // ---- q fragment (16 f32) with scale 0.25; single-touch -> nontemporal
    const float* qp = q + (((size_t)blk << 6) + (size_t)t) * 96 + n * 16;
    float qf[16];
#pragma unroll
    for (int v = 0; v < 4; ++v) {
        const f32x4 qv = __builtin_nontemporal_load((const f32x4*)qp + v);
        qf[4 * v + 0] = qv.x * 0.25f;    // SCALE = HD^-0.5 = 0.25
        qf[4 * v + 1] = qv.y * 0.25f;
        qf[4 * v + 2] = qv.z * 0.25f;
        qf[4 * v + 3] = qv.w * 0.25f;
    }

    // staging map: float4 index g = tid + 384*v over pencil [t][c] (c=0..23)
    const int c0 = tid % 24;             // channel chunk
    const int t0 = tid / 24;             // t-row 0..15; per v add 16
    const int swz = c0 & 7;

    // pencil base pointer for window slot p (di = p/3-1, dj = p%3-1);
    // OOB pencils use the (block-uniform) center address, scores masked later.
    auto kbase = [&](int p) -> const float4* {
        const int hh = h + p / 3 - 1;
        const int ww = w + p % 3 - 1;
        const bool ok = ((unsigned)hh < 64u) & ((unsigned)ww < 64u);
        const int hc = ok ? hh : h;
        const int wc = ok ? ww : w;
        return (const float4*)(k + ((((size_t)b * 64 + hc) * 64 + wc) * 64) * 96);
    };

    // prefetch pencil 0
    float4 kv[4];
    {
        const float4* kp = kbase(0);
#pragma unroll
        for (int v = 0; v < 4; ++v) kv[v] = kp[tid + 384 * v];
    }

    // streaming softmax accumulators (no max-subtraction: |s| <~ 8, fp32-safe)
    float sum = 0.f, xa = 0.f, ya = 0.f, za = 0.f;

#pragma unroll
    for (int p = 0; p < 9; ++p) {
        const int di = p / 3 - 1;
        const int dj = p % 3 - 1;
        const bool vHW = ((unsigned)(h + di) < 64u) && ((unsigned)(w + dj) < 64u);

        __syncthreads();               // previous iteration's LDS reads done
#pragma unroll
        for (int v = 0; v < 4; ++v)
            lds[c0 * 64 + ((t0 + 16 * v) ^ swz)] = kv[v];
        __syncthreads();               // staging visible

        if (p < 8) {                   // prefetch NEXT pencil under this compute
            const float4* kn = kbase(p + 1);
#pragma unroll
            for (int v = 0; v < 4; ++v) kv[v] = kn[tid + 384 * v];
        }

        // 3 dot products (dl = -1,0,+1) from LDS, folded into exp-sum
#pragma unroll
        for (int dl = -1; dl <= 1; ++dl) {
            const int tt = t + dl;
            const bool valid = vHW && ((unsigned)tt < 64u);
            const int tc = tt < 0 ? 0 : (tt > 63 ? 63 : tt);
            float s = 0.f;
#pragma unroll
            for (int v = 0; v < 4; ++v) {
                const int c = 4 * n + v;
                const float4 kx = lds[c * 64 + (tc ^ (c & 7))];
                s += qf[4 * v + 0] * kx.x;
                s += qf[4 * v + 1] * kx.y;
                s += qf[4 * v + 2] * kx.z;
                s += qf[4 * v + 3] * kx.w;
            }
            s = valid ? s : 0.f;       // zero-padded k => score 0, rpb still added
            const float e = __expf(s + rbs[n * 27 + 3 * p + (dl + 1)]);
            sum += e;
            xa += e * (float)di;       // di,dj,dl in {-1,0,1}: folds to add/sub
            ya += e * (float)dj;
            za += e * (float)dl;
        }
    }

    const float inv = 1.0f / sum;

    // ---- store: out[b][n*3+axis][h][w][t] ; consecutive t => coalesced 4B/lane
    const size_t obase = ((((size_t)b * 18 + (size_t)(n * 3)) * 64 + h) * 64 + w) * 64 + t;
    __builtin_nontemporal_store(xa * inv, &out[obase]);
    __builtin_nontemporal_store(ya * inv, &out[obase + 262144]);
    __builtin_nontemporal_store(za * inv, &out[obase + 2 * 262144]);
}

extern "C" void kernel_launch(void* const* d_in, const int* in_sizes, int n_in,
                              void* d_out, int out_size, void* d_ws, size_t ws_size,
                              hipStream_t stream) {
    const float* q   = (const float*)d_in[0];
    const float* k   = (const float*)d_in[1];
    const float* rpb = (const float*)d_in[2];
    float* out = (float*)d_out;
    (void)in_sizes; (void)n_in; (void)out_size; (void)d_ws; (void)ws_size;

    dim3 grid(2 * 64 * 64);   // one block per (b, h, w) pencil
    dim3 block(384);          // (head, t) = 6 x 64
    natt3d_kernel<<<grid, block, 0, stream>>>(q, k, rpb, out);
}

// Round 3
// 1116.590 us; speedup vs baseline: 1.0263x; 1.0263x over previous
//
#include <hip/hip_runtime.h>

// 3D neighborhood attention, window 3x3x3, over [B=2, 64,64,64, C=96], NH=6, HD=16.
// Inputs (float32): q [B,H,W,T,C], k [B,H,W,T,C], rpb [6,3,3,3].
// Output (float32): [B, 18, H, W, T]  (channel = head*3 + axis, axis in {di,dj,dl}).
//
// R6: R5 post-mortem fixes.
// (a) Drop nontemporal STORES: rocprof showed WRITE_SIZE = 2.0 GB for a 37.7 MB
//     output (53x amplification) -- the NT hint defeated TCC write coalescing.
//     Plain stores restore full-line write-back (~320 us of HBM time freed).
// (b) Column-major-within-XCD block order: R5's row-major chunk needed 4.7 MB
//     L2-resident for h-reuse (> 4 MiB/XCD); FETCH showed k re-fetched 5.7x.
//     Now 16 consecutive same-XCD blocks = one w-column of 16 h-rows; sliding
//     working set = 3 w-cols x 16 pencils x 24.6 KB = 1.2 MB << 4 MiB L2.
//     Expected fetch: ~227 MB k + 201 MB q (vs 1.34 GB measured in R5).
// (c) Keep: NT q loads (read-once), software-pipelined pencil prefetch,
//     streaming exp-sum softmax, rpb in LDS, swizzled conflict-free LDS layout.

typedef float f32x4 __attribute__((ext_vector_type(4)));

__global__ __launch_bounds__(384, 7) void natt3d_kernel(
    const float* __restrict__ q, const float* __restrict__ k,
    const float* __restrict__ rpb, float* __restrict__ out)
{
    // [c][t ^ (c&7)] in float4 units: c = 0..23 (16B channel chunk), t = 0..63.
    // Reads (fixed c, lane t): 16B-stride dense permutation -> conflict-free.
    // Writes (c fast across lanes): XOR spreads bank groups.
    __shared__ float4 lds[24 * 64];   // 24576 B
    __shared__ float rbs[6 * 27];     // rpb staged once, broadcast ds_reads

    // Block order: xcd = bid&7 (round-robin dispatch); within each XCD's 1024
    // blocks, walk column-major: 16 h-rows per XCD, w advances every 16 blocks.
    // row = global (b,h) row in 0..127; bijective.
    const int bid = (int)blockIdx.x;
    const int xcd = bid & 7;
    const int idx = bid >> 3;            // 0..1023 within XCD
    const int w   = idx >> 4;            // 0..63, slow axis
    const int row = (xcd << 4) | (idx & 15);
    const int b = row >> 6;
    const int h = row & 63;
    const int blk = (b << 12) | (h << 6) | w;   // linear (b,h,w) for addressing
    const int tid = (int)threadIdx.x;
    const int n = tid >> 6;              // head 0..5 (wave-uniform)
    const int t = tid & 63;              // lane id = t

    if (tid < 6 * 27) rbs[tid] = rpb[tid];   // visible after first barrier

    // ---- q fragment (16 f32) with scale 0.25; single-touch -> nontemporal
    const float* qp = q + (((size_t)blk << 6) + (size_t)t) * 96 + n * 16;
    float qf[16];
#pragma unroll
    for (int v = 0; v < 4; ++v) {
        const f32x4 qv = __builtin_nontemporal_load((const f32x4*)qp + v);
        qf[4 * v + 0] = qv.x * 0.25f;    // SCALE = HD^-0.5 = 0.25
        qf[4 * v + 1] = qv.y * 0.25f;
        qf[4 * v + 2] = qv.z * 0.25f;
        qf[4 * v + 3] = qv.w * 0.25f;
    }

    // staging map: float4 index g = tid + 384*v over pencil [t][c] (c=0..23)
    const int c0 = tid % 24;             // channel chunk
    const int t0 = tid / 24;             // t-row 0..15; per v add 16
    const int swz = c0 & 7;

    // pencil base pointer for window slot p (di = p/3-1, dj = p%3-1);
    // OOB pencils use the (block-uniform) center address, scores masked later.
    auto kbase = [&](int p) -> const float4* {
        const int hh = h + p / 3 - 1;
        const int ww = w + p % 3 - 1;
        const bool ok = ((unsigned)hh < 64u) & ((unsigned)ww < 64u);
        const int hc = ok ? hh : h;
        const int wc = ok ? ww : w;
        return (const float4*)(k + ((((size_t)b * 64 + hc) * 64 + wc) * 64) * 96);
    };

    // prefetch pencil 0
    float4 kv[4];
    {
        const float4* kp = kbase(0);
#pragma unroll
        for (int v = 0; v < 4; ++v) kv[v] = kp[tid + 384 * v];
    }

    // streaming softmax accumulators (no max-subtraction: |s| <~ 8, fp32-safe)
    float sum = 0.f, xa = 0.f, ya = 0.f, za = 0.f;

#pragma unroll
    for (int p = 0; p < 9; ++p) {
        const int di = p / 3 - 1;
        const int dj = p % 3 - 1;
        const bool vHW = ((unsigned)(h + di) < 64u) && ((unsigned)(w + dj) < 64u);

        __syncthreads();               // previous iteration's LDS reads done
#pragma unroll
        for (int v = 0; v < 4; ++v)
            lds[c0 * 64 + ((t0 + 16 * v) ^ swz)] = kv[v];
        __syncthreads();               // staging visible

        if (p < 8) {                   // prefetch NEXT pencil under this compute
            const float4* kn = kbase(p + 1);
#pragma unroll
            for (int v = 0; v < 4; ++v) kv[v] = kn[tid + 384 * v];
        }

        // 3 dot products (dl = -1,0,+1) from LDS, folded into exp-sum
#pragma unroll
        for (int dl = -1; dl <= 1; ++dl) {
            const int tt = t + dl;
            const bool valid = vHW && ((unsigned)tt < 64u);
            const int tc = tt < 0 ? 0 : (tt > 63 ? 63 : tt);
            float s = 0.f;
#pragma unroll
            for (int v = 0; v < 4; ++v) {
                const int c = 4 * n + v;
                const float4 kx = lds[c * 64 + (tc ^ (c & 7))];
                s += qf[4 * v + 0] * kx.x;
                s += qf[4 * v + 1] * kx.y;
                s += qf[4 * v + 2] * kx.z;
                s += qf[4 * v + 3] * kx.w;
            }
            s = valid ? s : 0.f;       // zero-padded k => score 0, rpb still added
            const float e = __expf(s + rbs[n * 27 + 3 * p + (dl + 1)]);
            sum += e;
            xa += e * (float)di;       // di,dj,dl in {-1,0,1}: folds to add/sub
            ya += e * (float)dj;
            za += e * (float)dl;
        }
    }

    const float inv = 1.0f / sum;

    // ---- store: out[b][n*3+axis][h][w][t] ; consecutive t => coalesced 4B/lane
    // Plain stores (NOT nontemporal): full-line coalesced write-back.
    const size_t obase = ((((size_t)b * 18 + (size_t)(n * 3)) * 64 + h) * 64 + w) * 64 + t;
    out[obase]              = xa * inv;
    out[obase + 262144]     = ya * inv;
    out[obase + 2 * 262144] = za * inv;
}

extern "C" void kernel_launch(void* const* d_in, const int* in_sizes, int n_in,
                              void* d_out, int out_size, void* d_ws, size_t ws_size,
                              hipStream_t stream) {
    const float* q   = (const float*)d_in[0];
    const float* k   = (const float*)d_in[1];
    const float* rpb = (const float*)d_in[2];
    float* out = (float*)d_out;
    (void)in_sizes; (void)n_in; (void)out_size; (void)d_ws; (void)ws_size;

    dim3 grid(2 * 64 * 64);   // one block per (b, h, w) pencil
    dim3 block(384);          // (head, t) = 6 x 64
    natt3d_kernel<<<grid, block, 0, stream>>>(q, k, rpb, out);
}

// Round 6
// 942.383 us; speedup vs baseline: 1.2160x; 1.1849x over previous
//
#include <hip/hip_runtime.h>

// 3D neighborhood attention, window 3x3x3, over [B=2, 64,64,64, C=96], NH=6, HD=16.
// Inputs (float32): q [B,H,W,T,C], k [B,H,W,T,C], rpb [6,3,3,3].
// Output (float32): [B, 18, H, W, T]  (channel = head*3 + axis, axis in {di,dj,dl}).
//
// R7: spill-elimination round (2nd resubmit — GPU acquisition timeouts).
// Evidence: R6 showed VGPR_Count=36 == exact minimum live set (qf16+kv16+4acc),
// WRITE_SIZE=1.9GB for a 37.7MB output, and total traffic 3.25GB > the 2.05GB
// zero-reuse worst case. Theory: __launch_bounds__(384,7) (added in R5) imposed
// a ~36-40 VGPR cap -> kv/temps spilled to scratch -> ~1.8GB scratch writes +
// read-misses through TCC. Fixes:
//   (a) __launch_bounds__(384, 4): cap >=85 VGPR, still 5 blocks/CU (LDS-bound).
//   (b) p-loop rolled (#pragma unroll 1) so the compiler can't hoist all 9
//       pencil prefetches into 144 registers and blow the budget.
//   (c) plain q loads (NT evict-first hurt cross-wave q line reuse; NT fully
//       removed from suspect list).
// Keep: software-pipelined pencil prefetch, column-major-within-XCD block walk,
// streaming exp-sum softmax, swizzled conflict-free LDS (bank conflicts = 0).

__global__ __launch_bounds__(384, 4) void natt3d_kernel(
    const float* __restrict__ q, const float* __restrict__ k,
    const float* __restrict__ rpb, float* __restrict__ out)
{
    // [c][t ^ (c&7)] in float4 units: c = 0..23 (16B channel chunk), t = 0..63.
    __shared__ float4 lds[24 * 64];   // 24576 B
    __shared__ float rbs[6 * 27];     // rpb staged once, broadcast ds_reads

    // Block order: xcd = bid&7 (round-robin dispatch); within each XCD's 1024
    // blocks, walk column-major: 16 h-rows per XCD, w advances every 16 blocks.
    const int bid = (int)blockIdx.x;
    const int xcd = bid & 7;
    const int idx = bid >> 3;            // 0..1023 within XCD
    const int w   = idx >> 4;            // 0..63, slow axis
    const int row = (xcd << 4) | (idx & 15);
    const int b = row >> 6;
    const int h = row & 63;
    const int blk = (b << 12) | (h << 6) | w;   // linear (b,h,w) for addressing
    const int tid = (int)threadIdx.x;
    const int n = tid >> 6;              // head 0..5 (wave-uniform)
    const int t = tid & 63;              // lane id = t

    if (tid < 6 * 27) rbs[tid] = rpb[tid];   // visible after first barrier

    // ---- q fragment (16 f32) with scale 0.25
    const float* qp = q + (((size_t)blk << 6) + (size_t)t) * 96 + n * 16;
    float qf[16];
#pragma unroll
    for (int v = 0; v < 4; ++v) {
        const float4 qv = *((const float4*)qp + v);
        qf[4 * v + 0] = qv.x * 0.25f;    // SCALE = HD^-0.5 = 0.25
        qf[4 * v + 1] = qv.y * 0.25f;
        qf[4 * v + 2] = qv.z * 0.25f;
        qf[4 * v + 3] = qv.w * 0.25f;
    }

    // staging map: float4 index g = tid + 384*v over pencil [t][c] (c=0..23)
    const int c0 = tid % 24;             // channel chunk
    const int t0 = tid / 24;             // t-row 0..15; per v add 16
    const int swz = c0 & 7;

    // pencil base pointer for window slot p (di = p/3-1, dj = p%3-1);
    // OOB pencils use the (block-uniform) center address, scores masked later.
    auto kbase = [&](int p) -> const float4* {
        const int hh = h + p / 3 - 1;
        const int ww = w + p % 3 - 1;
        const bool ok = ((unsigned)hh < 64u) & ((unsigned)ww < 64u);
        const int hc = ok ? hh : h;
        const int wc = ok ? ww : w;
        return (const float4*)(k + ((((size_t)b * 64 + hc) * 64 + wc) * 64) * 96);
    };

    // prefetch pencil 0
    float4 kv[4];
    {
        const float4* kp = kbase(0);
#pragma unroll
        for (int v = 0; v < 4; ++v) kv[v] = kp[tid + 384 * v];
    }

    // streaming softmax accumulators (no max-subtraction: |s| <~ 8, fp32-safe)
    float sum = 0.f, xa = 0.f, ya = 0.f, za = 0.f;

#pragma unroll 1
    for (int p = 0; p < 9; ++p) {
        const int di = p / 3 - 1;
        const int dj = p % 3 - 1;
        const bool vHW = ((unsigned)(h + di) < 64u) && ((unsigned)(w + dj) < 64u);

        __syncthreads();               // previous iteration's LDS reads done
#pragma unroll
        for (int v = 0; v < 4; ++v)
            lds[c0 * 64 + ((t0 + 16 * v) ^ swz)] = kv[v];
        __syncthreads();               // staging visible

        if (p < 8) {                   // prefetch NEXT pencil under this compute
            const float4* kn = kbase(p + 1);
#pragma unroll
            for (int v = 0; v < 4; ++v) kv[v] = kn[tid + 384 * v];
        }

        // 3 dot products (dl = -1,0,+1) from LDS, folded into exp-sum
#pragma unroll
        for (int dl = -1; dl <= 1; ++dl) {
            const int tt = t + dl;
            const bool valid = vHW && ((unsigned)tt < 64u);
            const int tc = tt < 0 ? 0 : (tt > 63 ? 63 : tt);
            float s = 0.f;
#pragma unroll
            for (int v = 0; v < 4; ++v) {
                const int c = 4 * n + v;
                const float4 kx = lds[c * 64 + (tc ^ (c & 7))];
                s += qf[4 * v + 0] * kx.x;
                s += qf[4 * v + 1] * kx.y;
                s += qf[4 * v + 2] * kx.z;
                s += qf[4 * v + 3] * kx.w;
            }
            s = valid ? s : 0.f;       // zero-padded k => score 0, rpb still added
            const float e = __expf(s + rbs[n * 27 + 3 * p + (dl + 1)]);
            sum += e;
            xa += e * (float)di;       // di,dj,dl in {-1,0,1}: folds to add/sub
            ya += e * (float)dj;
            za += e * (float)dl;
        }
    }

    const float inv = 1.0f / sum;

    // ---- store: out[b][n*3+axis][h][w][t] ; consecutive t => coalesced 4B/lane
    const size_t obase = ((((size_t)b * 18 + (size_t)(n * 3)) * 64 + h) * 64 + w) * 64 + t;
    out[obase]              = xa * inv;
    out[obase + 262144]     = ya * inv;
    out[obase + 2 * 262144] = za * inv;
}

extern "C" void kernel_launch(void* const* d_in, const int* in_sizes, int n_in,
                              void* d_out, int out_size, void* d_ws, size_t ws_size,
                              hipStream_t stream) {
    const float* q   = (const float*)d_in[0];
    const float* k   = (const float*)d_in[1];
    const float* rpb = (const float*)d_in[2];
    float* out = (float*)d_out;
    (void)in_sizes; (void)n_in; (void)out_size; (void)d_ws; (void)ws_size;

    dim3 grid(2 * 64 * 64);   // one block per (b, h, w) pencil
    dim3 block(384);          // (head, t) = 6 x 64
    natt3d_kernel<<<grid, block, 0, stream>>>(q, k, rpb, out);
}